// Round 5
// baseline (475.964 us; speedup 1.0000x reference)
//
#include <hip/hip_runtime.h>
#include <hip/hip_bf16.h>
#include <string.h>

#define BATCH 8
#define DM 1024
#define NS 64
#define SL 2048
#define NC 32
#define TC 64   // SL/NC

typedef float v2f __attribute__((ext_vector_type(2)));

// ws layout (floats):
//  BuT: [B][SL][NS]  f32  off 0         (4MB)
//  CuT: [B][SL][NS]  f32  off 1048576   (4MB)
//  W  : [B][SL][NS]  f32  off 2097152   (4MB)   Cu * a^((l%TC)+1)
//  E  : [B][NC][DM][NS] bf16 at float-off 3145728 (32MB; becomes HS in place)

static __device__ inline v2f bfpair_to_v2f(unsigned int p) {
    unsigned int lo = p << 16, hi = p & 0xffff0000u;
    v2f r;
    r.x = __uint_as_float(lo);
    r.y = __uint_as_float(hi);
    return r;
}

// ---------------- kernel 1: Bu/Cu projections (transposed) + W ----------------
// grid (SL/32, BATCH), block 256. No LDS: u via wave-uniform loads, B/C coalesced.
__global__ __launch_bounds__(256) void k_bucu(const float* __restrict__ u,
                                              const float* __restrict__ A,
                                              const float* __restrict__ B,
                                              const float* __restrict__ C,
                                              float* __restrict__ BuT,
                                              float* __restrict__ CuT,
                                              float* __restrict__ W)
{
    const int b  = blockIdx.y;
    const int l0 = blockIdx.x * 32;
    const int t  = threadIdx.x;
    const int n  = t & 63;
    const int g  = t >> 6;                 // wave id: wave-uniform
    const int lb = l0 + g * 8;             // 8 l's per thread, wave-uniform

    const float* Bp = B + n;
    const float* Cp = C + n;
    const float* ub = u + (size_t)b * DM * SL + lb;

    v2f aB[4], aC[4];
#pragma unroll
    for (int i = 0; i < 4; i++) { aB[i] = (v2f){0.f, 0.f}; aC[i] = (v2f){0.f, 0.f}; }

#pragma unroll 1
    for (int d0 = 0; d0 < DM; d0 += 32) {
#pragma unroll
        for (int dd = 0; dd < 32; dd++) {
            float bv = Bp[(size_t)(d0 + dd) * NS];      // coalesced across lanes
            float cv = Cp[(size_t)(d0 + dd) * NS];
            const float4* up = (const float4*)(ub + (size_t)(d0 + dd) * SL); // uniform
            float4 u0 = up[0], u1 = up[1];
            v2f bb = { bv, bv }, cc = { cv, cv };
            v2f w0 = { u0.x, u0.y }, w1 = { u0.z, u0.w };
            v2f w2 = { u1.x, u1.y }, w3 = { u1.z, u1.w };
            aB[0] = __builtin_elementwise_fma(bb, w0, aB[0]);
            aB[1] = __builtin_elementwise_fma(bb, w1, aB[1]);
            aB[2] = __builtin_elementwise_fma(bb, w2, aB[2]);
            aB[3] = __builtin_elementwise_fma(bb, w3, aB[3]);
            aC[0] = __builtin_elementwise_fma(cc, w0, aC[0]);
            aC[1] = __builtin_elementwise_fma(cc, w1, aC[1]);
            aC[2] = __builtin_elementwise_fma(cc, w2, aC[2]);
            aC[3] = __builtin_elementwise_fma(cc, w3, aC[3]);
        }
    }
    const float an = A[n * NS + n];
#pragma unroll
    for (int i = 0; i < 4; i++) {
        int l = lb + i * 2;
        size_t o0 = ((size_t)b * SL + l) * NS + n;
        size_t o1 = o0 + NS;
        BuT[o0] = aB[i].x;  BuT[o1] = aB[i].y;
        CuT[o0] = aC[i].x;  CuT[o1] = aC[i].y;
        W[o0] = aC[i].x * __powf(an, (float)((l & (TC - 1)) + 1));
        W[o1] = aC[i].y * __powf(an, (float)(((l + 1) & (TC - 1)) + 1));
    }
}

// ---------------- kernel 2: per-chunk local scan (zero init) ----------------
// grid (DM/256, NC, BATCH), block 256. u tile staged in XOR-swizzled LDS;
// y overwrites u in place; coalesced bulk load/store.
__global__ __launch_bounds__(256) void k_scan(const float* __restrict__ u,
                                              const float* __restrict__ A,
                                              const float* __restrict__ BuT,
                                              const float* __restrict__ CuT,
                                              __hip_bfloat16* __restrict__ E,
                                              float* __restrict__ y)
{
    __shared__ float su[256 * 64];        // 64KB, row r = d-row, col XOR (r&31)
    const int c  = blockIdx.y;
    const int b  = blockIdx.z;
    const int t  = threadIdx.x;
    const int d0 = blockIdx.x * 256;
    const int d  = d0 + t;
    const int l0 = c * TC;

    const float* usrc = u + ((size_t)b * DM + d0) * SL + l0;
    {   // stage u tile: 4096 float4, coalesced
#pragma unroll
        for (int p = 0; p < 16; p++) {
            int idx = p * 256 + t;
            int r = idx >> 4, f = idx & 15;
            float4 v = *(const float4*)(usrc + (size_t)r * SL + f * 4);
            int rs = r & 31, base = r * 64, fc = f * 4;
            su[base + ((fc + 0) ^ rs)] = v.x;
            su[base + ((fc + 1) ^ rs)] = v.y;
            su[base + ((fc + 2) ^ rs)] = v.z;
            su[base + ((fc + 3) ^ rs)] = v.w;
        }
    }

    v2f a2[32];
#pragma unroll
    for (int k = 0; k < 32; k++) {        // uniform -> scalar regs
        a2[k].x = A[(2 * k) * NS + (2 * k)];
        a2[k].y = A[(2 * k + 1) * NS + (2 * k + 1)];
    }

    v2f h[32];
#pragma unroll
    for (int k = 0; k < 32; k++) h[k] = (v2f){0.f, 0.f};

    const float* coefB = BuT + (size_t)(b * SL + l0) * NS;
    const float* coefC = CuT + (size_t)(b * SL + l0) * NS;

    __syncthreads();

    const int sw = t & 31;
    const int rowbase = t * 64;
#pragma unroll 2
    for (int l = 0; l < TC; l++) {
        float uv = su[rowbase + (l ^ sw)];
        v2f s = { uv, uv };
        const float4* bu4 = (const float4*)(coefB + (size_t)l * NS);  // uniform
        const float4* cu4 = (const float4*)(coefC + (size_t)l * NS);
        v2f y0 = {0.f, 0.f}, y1 = {0.f, 0.f};
#pragma unroll
        for (int k = 0; k < 16; k++) {
            float4 bu = bu4[k];
            float4 cu = cu4[k];
            v2f bu_lo = { bu.x, bu.y }, bu_hi = { bu.z, bu.w };
            v2f cu_lo = { cu.x, cu.y }, cu_hi = { cu.z, cu.w };
            int p = 2 * k, q = 2 * k + 1;
            h[p] = __builtin_elementwise_fma(a2[p], h[p], bu_lo * s);
            y0   = __builtin_elementwise_fma(cu_lo, h[p], y0);
            h[q] = __builtin_elementwise_fma(a2[q], h[q], bu_hi * s);
            y1   = __builtin_elementwise_fma(cu_hi, h[q], y1);
        }
        v2f yt = y0 + y1;
        su[rowbase + (l ^ sw)] = yt.x + yt.y;   // overwrite u with y
    }

    __syncthreads();

    {   // store y tile: coalesced
        float* ydst = y + ((size_t)b * DM + d0) * SL + l0;
#pragma unroll
        for (int p = 0; p < 16; p++) {
            int idx = p * 256 + t;
            int r = idx >> 4, f = idx & 15;
            int rs = r & 31, base = r * 64, fc = f * 4;
            float4 v;
            v.x = su[base + ((fc + 0) ^ rs)];
            v.y = su[base + ((fc + 1) ^ rs)];
            v.z = su[base + ((fc + 2) ^ rs)];
            v.w = su[base + ((fc + 3) ^ rs)];
            *(float4*)(ydst + (size_t)r * SL + f * 4) = v;
        }
    }

    // chunk-local end state, E[b][c][d][n] bf16 (128B contiguous per thread)
    __hip_bfloat162* e = (__hip_bfloat162*)(E + (((size_t)(b * NC + c) * DM) + d) * NS);
#pragma unroll
    for (int k = 0; k < 32; k++) {
        __hip_bfloat162 tp;
        tp.x = __float2bfloat16(h[k].x);
        tp.y = __float2bfloat16(h[k].y);
        e[k] = tp;
    }
}

// ---------------- kernel 3: prefix over chunks (E -> HS, in place) ----------------
__global__ __launch_bounds__(256) void k_prefix(const float* __restrict__ A,
                                                __hip_bfloat16* __restrict__ E)
{
    int g  = blockIdx.x * 256 + threadIdx.x;     // 0 .. 32767
    int ng = g & 3;
    int d  = (g >> 2) & (DM - 1);
    int b  = g >> 12;
    int n0 = ng * 16;

    v2f aT[8];
#pragma unroll
    for (int j = 0; j < 8; j++) {
        float a0 = A[(n0 + 2 * j) * NS + (n0 + 2 * j)];
        float a1 = A[(n0 + 2 * j + 1) * NS + (n0 + 2 * j + 1)];
        aT[j].x = __powf(a0, (float)TC);
        aT[j].y = __powf(a1, (float)TC);
    }

    v2f hs[8];
#pragma unroll
    for (int j = 0; j < 8; j++) hs[j] = (v2f){0.f, 0.f};

#pragma unroll 1
    for (int c = 0; c < NC; c++) {
        unsigned int* p = (unsigned int*)(E + (((size_t)b * NC + c) * DM + d) * NS + n0);
        uint4 e0 = *(uint4*)p;
        uint4 e1 = *(uint4*)(p + 4);
        unsigned int ew[8] = { e0.x, e0.y, e0.z, e0.w, e1.x, e1.y, e1.z, e1.w };
        unsigned int sw[8];
#pragma unroll
        for (int j = 0; j < 8; j++) {
            __hip_bfloat162 tp;
            tp.x = __float2bfloat16(hs[j].x);
            tp.y = __float2bfloat16(hs[j].y);
            unsigned int w;
            memcpy(&w, &tp, 4);
            sw[j] = w;
        }
        uint4 s0 = { sw[0], sw[1], sw[2], sw[3] };
        uint4 s1 = { sw[4], sw[5], sw[6], sw[7] };
        *(uint4*)p = s0;
        *(uint4*)(p + 4) = s1;
#pragma unroll
        for (int j = 0; j < 8; j++)
            hs[j] = __builtin_elementwise_fma(aT[j], hs[j], bfpair_to_v2f(ew[j]));
    }
}

// ---------------- kernel 4: cross-chunk correction ----------------
// grid (DM/256, NC-1, BATCH), block 256. y RMW via XOR-swizzled LDS tile.
__global__ __launch_bounds__(256) void k_corr(const __hip_bfloat16* __restrict__ HS,
                                              const float* __restrict__ W,
                                              float* __restrict__ y)
{
    __shared__ float sy[256 * 64];        // 64KB
    const int c  = blockIdx.y + 1;        // chunk 0 has zero start state
    const int b  = blockIdx.z;
    const int t  = threadIdx.x;
    const int d0 = blockIdx.x * 256;
    const int d  = d0 + t;
    const int l0 = c * TC;

    float* ybase = y + ((size_t)b * DM + d0) * SL + l0;
    {   // stage y tile: coalesced
#pragma unroll
        for (int p = 0; p < 16; p++) {
            int idx = p * 256 + t;
            int r = idx >> 4, f = idx & 15;
            float4 v = *(const float4*)(ybase + (size_t)r * SL + f * 4);
            int rs = r & 31, base = r * 64, fc = f * 4;
            sy[base + ((fc + 0) ^ rs)] = v.x;
            sy[base + ((fc + 1) ^ rs)] = v.y;
            sy[base + ((fc + 2) ^ rs)] = v.z;
            sy[base + ((fc + 3) ^ rs)] = v.w;
        }
    }

    v2f hs[32];
    {
        const unsigned int* pH = (const unsigned int*)(HS + (((size_t)b * NC + c) * DM + d) * NS);
#pragma unroll
        for (int q = 0; q < 8; q++) {
            uint4 v = *(const uint4*)(pH + q * 4);
            hs[q * 4 + 0] = bfpair_to_v2f(v.x);
            hs[q * 4 + 1] = bfpair_to_v2f(v.y);
            hs[q * 4 + 2] = bfpair_to_v2f(v.z);
            hs[q * 4 + 3] = bfpair_to_v2f(v.w);
        }
    }

    const float* wBase = W + (size_t)(b * SL + l0) * NS;

    __syncthreads();

    const int sw = t & 31;
    const int rowbase = t * 64;
#pragma unroll 2
    for (int l = 0; l < TC; l++) {
        const float4* w4 = (const float4*)(wBase + (size_t)l * NS);   // uniform
        v2f y0 = {0.f, 0.f}, y1 = {0.f, 0.f};
#pragma unroll
        for (int k = 0; k < 16; k++) {
            float4 w = w4[k];
            v2f w_lo = { w.x, w.y }, w_hi = { w.z, w.w };
            y0 = __builtin_elementwise_fma(w_lo, hs[2 * k],     y0);
            y1 = __builtin_elementwise_fma(w_hi, hs[2 * k + 1], y1);
        }
        v2f yt = y0 + y1;
        sy[rowbase + (l ^ sw)] += yt.x + yt.y;
    }

    __syncthreads();

    {   // store y tile back: coalesced
#pragma unroll
        for (int p = 0; p < 16; p++) {
            int idx = p * 256 + t;
            int r = idx >> 4, f = idx & 15;
            int rs = r & 31, base = r * 64, fc = f * 4;
            float4 v;
            v.x = sy[base + ((fc + 0) ^ rs)];
            v.y = sy[base + ((fc + 1) ^ rs)];
            v.z = sy[base + ((fc + 2) ^ rs)];
            v.w = sy[base + ((fc + 3) ^ rs)];
            *(float4*)(ybase + (size_t)r * SL + f * 4) = v;
        }
    }
}

extern "C" void kernel_launch(void* const* d_in, const int* in_sizes, int n_in,
                              void* d_out, int out_size, void* d_ws, size_t ws_size,
                              hipStream_t stream) {
    const float* u = (const float*)d_in[1];
    const float* A = (const float*)d_in[2];
    const float* B = (const float*)d_in[3];
    const float* C = (const float*)d_in[4];
    float* y = (float*)d_out;

    float* ws  = (float*)d_ws;
    float* BuT = ws;
    float* CuT = ws + 1048576;
    float* W   = ws + 2097152;
    __hip_bfloat16* E = (__hip_bfloat16*)(ws + 3145728);

    k_bucu<<<dim3(SL / 32, BATCH), 256, 0, stream>>>(u, A, B, C, BuT, CuT, W);
    k_scan<<<dim3(DM / 256, NC, BATCH), 256, 0, stream>>>(u, A, BuT, CuT, E, y);
    k_prefix<<<dim3(BATCH * DM * 4 / 256), 256, 0, stream>>>(A, E);
    k_corr<<<dim3(DM / 256, NC - 1, BATCH), 256, 0, stream>>>(E, W, y);
}

// Round 7
// 265.768 us; speedup vs baseline: 1.7909x; 1.7909x over previous
//
#include <hip/hip_runtime.h>
#include <hip/hip_bf16.h>
#include <string.h>

#define BATCH 8
#define DM 1024
#define NS 64
#define SL 2048
#define NC 32
#define TC 64

typedef __attribute__((ext_vector_type(8))) short bf16x8;
typedef __attribute__((ext_vector_type(4))) float f32x4;
typedef float v2f __attribute__((ext_vector_type(2)));

__device__ inline unsigned short f2bf(float f) {
    union { float f; unsigned u; } v; v.f = f;
    return (unsigned short)((v.u + 0x7fffu + ((v.u >> 16) & 1u)) >> 16);
}
__device__ inline float bf2f(unsigned short h) {
    return __uint_as_float(((unsigned)h) << 16);
}
static __device__ inline v2f bfpair_to_v2f(unsigned int p) {
    unsigned int lo = p << 16, hi = p & 0xffff0000u;
    v2f r; r.x = __uint_as_float(lo); r.y = __uint_as_float(hi); return r;
}

// ws layout (bytes):
//  BuT bf16 [B][SL][NS]      off  0MB  (2MB)
//  CuT bf16 [B][SL][NS]      off  2MB  (2MB)
//  BT  bf16 [NS][DM]         off  4MB  (128KB)
//  CT  bf16 [NS][DM]         off  4MB+128KB
//  G   bf16 [B][NC][64][64]  off  5MB  (2MB)
//  Bv  bf16 [B][NC][64][64]  off  7MB  (2MB)
//  Wc  bf16 [B][NC][64][64]  off  9MB  (2MB)
//  E   bf16 [B][NC][DM][NS]  off 11MB  (32MB)   -> total 43MB

// ---------- kernel 0: transpose B,C -> BT,CT bf16 [n][d] ----------
__global__ __launch_bounds__(256) void k_prep(const float* __restrict__ Bm,
                                              const float* __restrict__ Cm,
                                              unsigned short* __restrict__ BT,
                                              unsigned short* __restrict__ CT)
{
    __shared__ float sT[64][65];
    const float* src = blockIdx.y ? Cm : Bm;
    unsigned short* dst = blockIdx.y ? CT : BT;
    const int d0 = blockIdx.x * 64, t = threadIdx.x;
    {
        int r = t >> 2, f = (t & 3) * 16;
#pragma unroll
        for (int i = 0; i < 4; i++) {
            float4 v = *(const float4*)&src[(size_t)(d0 + r) * NS + f + i * 4];
            sT[r][f + i * 4 + 0] = v.x; sT[r][f + i * 4 + 1] = v.y;
            sT[r][f + i * 4 + 2] = v.z; sT[r][f + i * 4 + 3] = v.w;
        }
    }
    __syncthreads();
    {
        int n = t >> 2, dq = (t & 3) * 16;
        unsigned pk[8];
#pragma unroll
        for (int k = 0; k < 8; k++) {
            unsigned short a = f2bf(sT[dq + 2 * k][n]);
            unsigned short bb = f2bf(sT[dq + 2 * k + 1][n]);
            pk[k] = (unsigned)a | ((unsigned)bb << 16);
        }
        uint4 v0 = { pk[0], pk[1], pk[2], pk[3] };
        uint4 v1 = { pk[4], pk[5], pk[6], pk[7] };
        *(uint4*)&dst[(size_t)n * DM + d0 + dq] = v0;
        *(uint4*)&dst[(size_t)n * DM + d0 + dq + 8] = v1;
    }
}

// ---------- kernel 1: Bu/Cu projections via MFMA ----------
// grid (SL/32, B), 256 thr. out[l][n] = sum_d u[d][l] * BC[n][d]
__global__ __launch_bounds__(256) void k_proj(const float* __restrict__ u,
                                              const unsigned short* __restrict__ BC, // [128][DM]
                                              unsigned short* __restrict__ BuT,
                                              unsigned short* __restrict__ CuT)
{
    __shared__ unsigned short sA[32 * 64];   // [l][d] swz
    __shared__ unsigned short sB[128 * 64];  // [n][d] swz
    const int b = blockIdx.y, l0 = blockIdx.x * 32, t = threadIdx.x;
    const int lane = t & 63, w = t >> 6, g = lane >> 4, m15 = lane & 15;

    f32x4 acc[2][2];
#pragma unroll
    for (int i = 0; i < 2; i++)
#pragma unroll
        for (int j = 0; j < 2; j++) acc[i][j] = (f32x4){0.f, 0.f, 0.f, 0.f};

#pragma unroll 1
    for (int d0 = 0; d0 < DM; d0 += 64) {
        __syncthreads();
        // stage A: u[d0..d0+64][l0..l0+32] -> sA[l][d] bf16 swizzled
#pragma unroll
        for (int p = 0; p < 2; p++) {
            int dd = p * 32 + (t >> 3), f = t & 7;
            float4 v = *(const float4*)&u[((size_t)b * DM + d0 + dd) * SL + l0 + f * 4];
            int l = f * 4;
            sA[(l + 0) * 64 + (((dd >> 3) ^ ((l + 0) & 7)) * 8) + (dd & 7)] = f2bf(v.x);
            sA[(l + 1) * 64 + (((dd >> 3) ^ ((l + 1) & 7)) * 8) + (dd & 7)] = f2bf(v.y);
            sA[(l + 2) * 64 + (((dd >> 3) ^ ((l + 2) & 7)) * 8) + (dd & 7)] = f2bf(v.z);
            sA[(l + 3) * 64 + (((dd >> 3) ^ ((l + 3) & 7)) * 8) + (dd & 7)] = f2bf(v.w);
        }
        // stage B: BC rows 0..127, cols d0..d0+64
#pragma unroll
        for (int p = 0; p < 4; p++) {
            int row = p * 32 + (t >> 3), c8 = t & 7;
            uint4 v = *(const uint4*)(BC + (size_t)row * DM + d0 + c8 * 8);
            *(uint4*)&sB[row * 64 + ((c8 ^ (row & 7)) * 8)] = v;
        }
        __syncthreads();
#pragma unroll
        for (int ks = 0; ks < 2; ks++) {
            bf16x8 af[2], bf[2];
#pragma unroll
            for (int mt = 0; mt < 2; mt++) {
                int r = mt * 16 + m15;
                af[mt] = *(const bf16x8*)&sA[r * 64 + (((ks * 4 + g) ^ (r & 7)) * 8)];
            }
#pragma unroll
            for (int nt = 0; nt < 2; nt++) {
                int r = w * 32 + nt * 16 + m15;
                bf[nt] = *(const bf16x8*)&sB[r * 64 + (((ks * 4 + g) ^ (r & 7)) * 8)];
            }
#pragma unroll
            for (int mt = 0; mt < 2; mt++)
#pragma unroll
                for (int nt = 0; nt < 2; nt++)
                    acc[mt][nt] = __builtin_amdgcn_mfma_f32_16x16x32_bf16(af[mt], bf[nt], acc[mt][nt], 0, 0, 0);
        }
    }
    // epilogue: C[m=l][n=wn]
#pragma unroll
    for (int mt = 0; mt < 2; mt++)
#pragma unroll
        for (int nt = 0; nt < 2; nt++) {
            int wn = w * 32 + nt * 16 + m15;
            unsigned short* dst = (wn < 64) ? BuT : CuT;
            int n = wn & 63;
#pragma unroll
            for (int r = 0; r < 4; r++) {
                int l = l0 + mt * 16 + g * 4 + r;
                dst[((size_t)b * SL + l) * NS + n] = f2bf(acc[mt][nt][r]);
            }
        }
}

// ---------- kernel 2: per-chunk G / Bv / Wc ----------
// grid (B*NC) blocks of 64 threads; thread = l.
__global__ __launch_bounds__(64) void k_g(const float* __restrict__ A,
                                          const unsigned short* __restrict__ BuT,
                                          const unsigned short* __restrict__ CuT,
                                          unsigned short* __restrict__ Gw,
                                          unsigned short* __restrict__ Bvw,
                                          unsigned short* __restrict__ Wcw)
{
    __shared__ unsigned short sBu[64 * 64];
    __shared__ unsigned short sG[64 * 64];
    __shared__ unsigned short sT[64 * 64];
    __shared__ float sAd[64];
    const int cc = blockIdx.x, b = cc >> 5, c = cc & 31;
    const int l = threadIdx.x, l0 = c * TC;

    sAd[l] = A[l * NS + l];
    // stage own Bu row (swizzled)
    const unsigned short* bsrc = BuT + ((size_t)b * SL + l0 + l) * NS;
#pragma unroll
    for (int q = 0; q < 8; q++) {
        uint4 v = *(const uint4*)(bsrc + q * 8);
        *(uint4*)&sBu[l * 64 + ((q ^ (l & 7)) * 8)] = v;
    }
    // zero own G row
    uint4 z = { 0, 0, 0, 0 };
#pragma unroll
    for (int q = 0; q < 8; q++) *(uint4*)&sG[l * 64 + q * 8] = z;
    // own Cu row -> regs
    float cu[64];
    const unsigned short* csrc = CuT + ((size_t)b * SL + l0 + l) * NS;
#pragma unroll
    for (int q = 0; q < 8; q++) {
        uint4 v = *(const uint4*)(csrc + q * 8);
        unsigned ww[4] = { v.x, v.y, v.z, v.w };
#pragma unroll
        for (int k = 0; k < 4; k++) {
            cu[q * 8 + 2 * k]     = bf2f((unsigned short)(ww[k] & 0xffff));
            cu[q * 8 + 2 * k + 1] = bf2f((unsigned short)(ww[k] >> 16));
        }
    }
    __syncthreads();
    float an[64];
#pragma unroll
    for (int n = 0; n < 64; n++) an[n] = sAd[n];
    // Bv column l: bu[l][:] * a^(63-l)  -> sT[n][l]
#pragma unroll
    for (int q = 0; q < 8; q++) {
        bf16x8 v = *(const bf16x8*)&sBu[l * 64 + ((q ^ (l & 7)) * 8)];
#pragma unroll
        for (int j = 0; j < 8; j++) {
            int n = q * 8 + j;
            float bu = bf2f((unsigned short)v[j]);
            float p = __powf(an[n], (float)(63 - l));
            sT[n * 64 + l] = f2bf(bu * p);
        }
    }
    // main G loop: CP = cu * a^(l-l'), descending l'
    float CP[64];
#pragma unroll
    for (int n = 0; n < 64; n++) CP[n] = cu[n];
#pragma unroll 1
    for (int lp = 63; lp >= 0; --lp) {
        if (lp <= l) {
            float acc = 0.f;
#pragma unroll
            for (int q = 0; q < 8; q++) {
                bf16x8 v = *(const bf16x8*)&sBu[lp * 64 + (((q ^ (lp & 7))) * 8)];
#pragma unroll
                for (int j = 0; j < 8; j++)
                    acc = fmaf(CP[q * 8 + j], bf2f((unsigned short)v[j]), acc);
            }
            sG[l * 64 + lp] = f2bf(acc);
#pragma unroll
            for (int n = 0; n < 64; n++) CP[n] *= an[n];
        }
    }
    __syncthreads();
    const size_t base = (size_t)cc * 4096;
#pragma unroll
    for (int q = 0; q < 8; q++)
        *(uint4*)(Gw + base + l * 64 + q * 8) = *(const uint4*)&sG[l * 64 + q * 8];
#pragma unroll
    for (int q = 0; q < 8; q++)
        *(uint4*)(Bvw + base + l * 64 + q * 8) = *(const uint4*)&sT[l * 64 + q * 8];
    // Wc row l = CP (= cu * a^(l+1))
#pragma unroll
    for (int q = 0; q < 8; q++) {
        unsigned pk[4];
#pragma unroll
        for (int k = 0; k < 4; k++)
            pk[k] = (unsigned)f2bf(CP[q * 8 + 2 * k]) | ((unsigned)f2bf(CP[q * 8 + 2 * k + 1]) << 16);
        uint4 v = { pk[0], pk[1], pk[2], pk[3] };
        *(uint4*)(Wcw + base + l * 64 + q * 8) = v;
    }
}

// ---------- kernel 3: Y_intra + E via MFMA ----------
// grid (4 dslab, NC, B), 256 thr. Y[d][l] = sum_l' u[d][l']G[l][l']; E[d][n] = sum_l' u[d][l']Bv[n][l']
__global__ __launch_bounds__(256) void k_chunk(const float* __restrict__ u,
                                               const unsigned short* __restrict__ Gw,
                                               const unsigned short* __restrict__ Bvw,
                                               unsigned short* __restrict__ Ew,
                                               float* __restrict__ y)
{
    __shared__ unsigned short sU[256 * 64];
    __shared__ unsigned short sG[64 * 64];
    __shared__ unsigned short sV[64 * 64];
    const int slab = blockIdx.x, c = blockIdx.y, b = blockIdx.z;
    const int d0 = slab * 256, l0 = c * TC;
    const int t = threadIdx.x, lane = t & 63, w = t >> 6, g = lane >> 4, m15 = lane & 15;

    {
        size_t gbase = ((size_t)(b * NC + c)) * 4096;
        int rr = t >> 3, c8 = t & 7;
#pragma unroll
        for (int p = 0; p < 2; p++) {
            int r = p * 32 + rr;
            uint4 gv = *(const uint4*)(Gw + gbase + r * 64 + c8 * 8);
            *(uint4*)&sG[r * 64 + ((c8 ^ (r & 7)) * 8)] = gv;
            uint4 vv = *(const uint4*)(Bvw + gbase + r * 64 + c8 * 8);
            *(uint4*)&sV[r * 64 + ((c8 ^ (r & 7)) * 8)] = vv;
        }
    }
#pragma unroll
    for (int p = 0; p < 16; p++) {
        int dd = p * 16 + (t >> 4), f = t & 15;
        float4 v = *(const float4*)&u[((size_t)b * DM + d0 + dd) * SL + l0 + f * 4];
        unsigned lo = (unsigned)f2bf(v.x) | ((unsigned)f2bf(v.y) << 16);
        unsigned hi = (unsigned)f2bf(v.z) | ((unsigned)f2bf(v.w) << 16);
        uint2 pk = { lo, hi };
        *(uint2*)&sU[dd * 64 + (((f >> 1) ^ (dd & 7)) * 8) + (f & 1) * 4] = pk;
    }
    __syncthreads();

    f32x4 accY[4][4], accE[4][4];
#pragma unroll
    for (int i = 0; i < 4; i++)
#pragma unroll
        for (int j = 0; j < 4; j++) {
            accY[i][j] = (f32x4){0.f, 0.f, 0.f, 0.f};
            accE[i][j] = (f32x4){0.f, 0.f, 0.f, 0.f};
        }

#pragma unroll
    for (int ks = 0; ks < 2; ks++) {
        bf16x8 af[4];
#pragma unroll
        for (int mt = 0; mt < 4; mt++) {
            int r = w * 64 + mt * 16 + m15;
            af[mt] = *(const bf16x8*)&sU[r * 64 + (((ks * 4 + g) ^ (r & 7)) * 8)];
        }
#pragma unroll
        for (int nt = 0; nt < 4; nt++) {
            int rg = nt * 16 + m15;
            bf16x8 bg = *(const bf16x8*)&sG[rg * 64 + (((ks * 4 + g) ^ (rg & 7)) * 8)];
            bf16x8 bv = *(const bf16x8*)&sV[rg * 64 + (((ks * 4 + g) ^ (rg & 7)) * 8)];
#pragma unroll
            for (int mt = 0; mt < 4; mt++) {
                accY[mt][nt] = __builtin_amdgcn_mfma_f32_16x16x32_bf16(af[mt], bg, accY[mt][nt], 0, 0, 0);
                accE[mt][nt] = __builtin_amdgcn_mfma_f32_16x16x32_bf16(af[mt], bv, accE[mt][nt], 0, 0, 0);
            }
        }
    }
#pragma unroll
    for (int mt = 0; mt < 4; mt++)
#pragma unroll
        for (int nt = 0; nt < 4; nt++)
#pragma unroll
            for (int r = 0; r < 4; r++) {
                int d = d0 + w * 64 + mt * 16 + g * 4 + r;
                int l = l0 + nt * 16 + m15;
                y[((size_t)b * DM + d) * SL + l] = accY[mt][nt][r];
                Ew[(((size_t)b * NC + c) * DM + d) * NS + nt * 16 + m15] = f2bf(accE[mt][nt][r]);
            }
}

// ---------- kernel 4: prefix over chunks (E -> HS in place), R5-proven ----------
__global__ __launch_bounds__(256) void k_prefix(const float* __restrict__ A,
                                                __hip_bfloat16* __restrict__ E)
{
    int gg = blockIdx.x * 256 + threadIdx.x;
    int ng = gg & 3;
    int d = (gg >> 2) & (DM - 1);
    int b = gg >> 12;
    int n0 = ng * 16;

    v2f aT[8];
#pragma unroll
    for (int j = 0; j < 8; j++) {
        float a0 = A[(n0 + 2 * j) * NS + (n0 + 2 * j)];
        float a1 = A[(n0 + 2 * j + 1) * NS + (n0 + 2 * j + 1)];
        aT[j].x = __powf(a0, (float)TC);
        aT[j].y = __powf(a1, (float)TC);
    }
    v2f hs[8];
#pragma unroll
    for (int j = 0; j < 8; j++) hs[j] = (v2f){0.f, 0.f};

#pragma unroll 1
    for (int c = 0; c < NC; c++) {
        unsigned int* p = (unsigned int*)(E + (((size_t)b * NC + c) * DM + d) * NS + n0);
        uint4 e0 = *(uint4*)p;
        uint4 e1 = *(uint4*)(p + 4);
        unsigned int ew[8] = { e0.x, e0.y, e0.z, e0.w, e1.x, e1.y, e1.z, e1.w };
        unsigned int sw[8];
#pragma unroll
        for (int j = 0; j < 8; j++) {
            __hip_bfloat162 tp;
            tp.x = __float2bfloat16(hs[j].x);
            tp.y = __float2bfloat16(hs[j].y);
            unsigned int wv; memcpy(&wv, &tp, 4);
            sw[j] = wv;
        }
        uint4 s0 = { sw[0], sw[1], sw[2], sw[3] };
        uint4 s1 = { sw[4], sw[5], sw[6], sw[7] };
        *(uint4*)p = s0;
        *(uint4*)(p + 4) = s1;
#pragma unroll
        for (int j = 0; j < 8; j++)
            hs[j] = __builtin_elementwise_fma(aT[j], hs[j], bfpair_to_v2f(ew[j]));
    }
}

// ---------- kernel 5: cross-chunk correction via MFMA ----------
// grid (4 dslab, NC-1, B). y[d][l] += sum_n HS[d][n] * Wc[l][n]
__global__ __launch_bounds__(256) void k_corr(const unsigned short* __restrict__ Ew,
                                              const unsigned short* __restrict__ Wcw,
                                              float* __restrict__ y)
{
    __shared__ unsigned short sH[256 * 64];
    __shared__ unsigned short sW[64 * 64];
    const int slab = blockIdx.x, c = blockIdx.y + 1, b = blockIdx.z;
    const int d0 = slab * 256, l0 = c * TC;
    const int t = threadIdx.x, lane = t & 63, w = t >> 6, g = lane >> 4, m15 = lane & 15;

    {
        int rr = t >> 3, c8 = t & 7;
#pragma unroll
        for (int p = 0; p < 8; p++) {
            int r = p * 32 + rr;
            uint4 v = *(const uint4*)(Ew + (((size_t)b * NC + c) * DM + d0 + r) * NS + c8 * 8);
            *(uint4*)&sH[r * 64 + ((c8 ^ (r & 7)) * 8)] = v;
        }
        size_t wbase = ((size_t)(b * NC + c)) * 4096;
#pragma unroll
        for (int p = 0; p < 2; p++) {
            int r = p * 32 + rr;
            uint4 v = *(const uint4*)(Wcw + wbase + r * 64 + c8 * 8);
            *(uint4*)&sW[r * 64 + ((c8 ^ (r & 7)) * 8)] = v;
        }
    }
    __syncthreads();

    f32x4 acc[4][4];
#pragma unroll
    for (int i = 0; i < 4; i++)
#pragma unroll
        for (int j = 0; j < 4; j++) acc[i][j] = (f32x4){0.f, 0.f, 0.f, 0.f};

#pragma unroll
    for (int ks = 0; ks < 2; ks++) {
        bf16x8 af[4];
#pragma unroll
        for (int mt = 0; mt < 4; mt++) {
            int r = w * 64 + mt * 16 + m15;
            af[mt] = *(const bf16x8*)&sH[r * 64 + (((ks * 4 + g) ^ (r & 7)) * 8)];
        }
#pragma unroll
        for (int nt = 0; nt < 4; nt++) {
            int rg = nt * 16 + m15;
            bf16x8 bw = *(const bf16x8*)&sW[rg * 64 + (((ks * 4 + g) ^ (rg & 7)) * 8)];
#pragma unroll
            for (int mt = 0; mt < 4; mt++)
                acc[mt][nt] = __builtin_amdgcn_mfma_f32_16x16x32_bf16(af[mt], bw, acc[mt][nt], 0, 0, 0);
        }
    }
#pragma unroll
    for (int mt = 0; mt < 4; mt++)
#pragma unroll
        for (int nt = 0; nt < 4; nt++)
#pragma unroll
            for (int r = 0; r < 4; r++) {
                int d = d0 + w * 64 + mt * 16 + g * 4 + r;
                int l = l0 + nt * 16 + m15;
                float* p = &y[((size_t)b * DM + d) * SL + l];
                *p = *p + acc[mt][nt][r];
            }
}

extern "C" void kernel_launch(void* const* d_in, const int* in_sizes, int n_in,
                              void* d_out, int out_size, void* d_ws, size_t ws_size,
                              hipStream_t stream) {
    const float* u = (const float*)d_in[1];
    const float* A = (const float*)d_in[2];
    const float* B = (const float*)d_in[3];
    const float* C = (const float*)d_in[4];
    float* y = (float*)d_out;

    char* base = (char*)d_ws;
    unsigned short* BuT = (unsigned short*)(base);
    unsigned short* CuT = (unsigned short*)(base + (2u << 20));
    unsigned short* BT  = (unsigned short*)(base + (4u << 20));            // [128][DM] with CT
    unsigned short* Gw  = (unsigned short*)(base + (5u << 20));
    unsigned short* Bvw = (unsigned short*)(base + (7u << 20));
    unsigned short* Wcw = (unsigned short*)(base + (9u << 20));
    unsigned short* Ew  = (unsigned short*)(base + (11u << 20));
    unsigned short* CT  = BT + (size_t)NS * DM;

    k_prep<<<dim3(DM / 64, 2), 256, 0, stream>>>(B, C, BT, CT);
    k_proj<<<dim3(SL / 32, BATCH), 256, 0, stream>>>(u, BT, BuT, CuT);
    k_g<<<dim3(BATCH * NC), 64, 0, stream>>>(A, BuT, CuT, Gw, Bvw, Wcw);
    k_chunk<<<dim3(4, NC, BATCH), 256, 0, stream>>>(u, Gw, Bvw, Ew, y);
    k_prefix<<<dim3(BATCH * DM * 4 / 256), 256, 0, stream>>>(A, (__hip_bfloat16*)Ew);
    k_corr<<<dim3(4, NC - 1, BATCH), 256, 0, stream>>>(Ew, Wcw, y);
}

// Round 8
// 130.887 us; speedup vs baseline: 3.6365x; 2.0305x over previous
//
#include <hip/hip_runtime.h>
#include <hip/hip_bf16.h>
#include <string.h>

#define BATCH 8
#define DM 1024
#define NS 64
#define SL 2048
#define NC 32
#define TC 64

typedef __attribute__((ext_vector_type(8))) short bf16x8;
typedef __attribute__((ext_vector_type(4))) float f32x4;
typedef float v2f __attribute__((ext_vector_type(2)));

__device__ inline unsigned short f2bf(float f) {
    union { float f; unsigned u; } v; v.f = f;
    return (unsigned short)((v.u + 0x7fffu + ((v.u >> 16) & 1u)) >> 16);
}
__device__ inline float bf2f(unsigned short h) {
    return __uint_as_float(((unsigned)h) << 16);
}
static __device__ inline v2f bfpair_to_v2f(unsigned int p) {
    unsigned int lo = p << 16, hi = p & 0xffff0000u;
    v2f r; r.x = __uint_as_float(lo); r.y = __uint_as_float(hi); return r;
}

// ws layout (bytes):
//  BuT bf16 [B][SL][NS]      off  0MB  (2MB)
//  CuT bf16 [B][SL][NS]      off  2MB  (2MB)
//  BT  bf16 [NS][DM]         off  4MB  (128KB)
//  CT  bf16 [NS][DM]         off  4MB+128KB
//  G   bf16 [B][NC][64][64]  off  5MB  (2MB)
//  Bv  bf16 [B][NC][64][64]  off  7MB  (2MB)
//  Wc  bf16 [B][NC][64][64]  off  9MB  (2MB)
//  E   bf16 [B][NC][DM][NS]  off 11MB  (32MB)   -> total 43MB

// ---------- kernel 0: transpose B,C -> BT,CT bf16 [n][d] ----------
__global__ __launch_bounds__(256) void k_prep(const float* __restrict__ Bm,
                                              const float* __restrict__ Cm,
                                              unsigned short* __restrict__ BT,
                                              unsigned short* __restrict__ CT)
{
    __shared__ float sT[64][65];
    const float* src = blockIdx.y ? Cm : Bm;
    unsigned short* dst = blockIdx.y ? CT : BT;
    const int d0 = blockIdx.x * 64, t = threadIdx.x;
    {
        int r = t >> 2, f = (t & 3) * 16;
#pragma unroll
        for (int i = 0; i < 4; i++) {
            float4 v = *(const float4*)&src[(size_t)(d0 + r) * NS + f + i * 4];
            sT[r][f + i * 4 + 0] = v.x; sT[r][f + i * 4 + 1] = v.y;
            sT[r][f + i * 4 + 2] = v.z; sT[r][f + i * 4 + 3] = v.w;
        }
    }
    __syncthreads();
    {
        int n = t >> 2, dq = (t & 3) * 16;
        unsigned pk[8];
#pragma unroll
        for (int k = 0; k < 8; k++) {
            unsigned short a = f2bf(sT[dq + 2 * k][n]);
            unsigned short bb = f2bf(sT[dq + 2 * k + 1][n]);
            pk[k] = (unsigned)a | ((unsigned)bb << 16);
        }
        uint4 v0 = { pk[0], pk[1], pk[2], pk[3] };
        uint4 v1 = { pk[4], pk[5], pk[6], pk[7] };
        *(uint4*)&dst[(size_t)n * DM + d0 + dq] = v0;
        *(uint4*)&dst[(size_t)n * DM + d0 + dq + 8] = v1;
    }
}

// ---------- kernel 1: Bu/Cu projections via MFMA ----------
// grid (SL/32, B), 256 thr. out[l][n] = sum_d u[d][l] * BC[n][d]
__global__ __launch_bounds__(256) void k_proj(const float* __restrict__ u,
                                              const unsigned short* __restrict__ BC, // [128][DM]
                                              unsigned short* __restrict__ BuT,
                                              unsigned short* __restrict__ CuT)
{
    __shared__ unsigned short sA[32 * 64];   // [l][d] swz
    __shared__ unsigned short sB[128 * 64];  // [n][d] swz
    const int b = blockIdx.y, l0 = blockIdx.x * 32, t = threadIdx.x;
    const int lane = t & 63, w = t >> 6, g = lane >> 4, m15 = lane & 15;

    f32x4 acc[2][2];
#pragma unroll
    for (int i = 0; i < 2; i++)
#pragma unroll
        for (int j = 0; j < 2; j++) acc[i][j] = (f32x4){0.f, 0.f, 0.f, 0.f};

#pragma unroll 1
    for (int d0 = 0; d0 < DM; d0 += 64) {
        __syncthreads();
        // stage A: u[d0..d0+64][l0..l0+32] -> sA[l][d] bf16 swizzled
#pragma unroll
        for (int p = 0; p < 2; p++) {
            int dd = p * 32 + (t >> 3), f = t & 7;
            float4 v = *(const float4*)&u[((size_t)b * DM + d0 + dd) * SL + l0 + f * 4];
            int l = f * 4;
            sA[(l + 0) * 64 + (((dd >> 3) ^ ((l + 0) & 7)) * 8) + (dd & 7)] = f2bf(v.x);
            sA[(l + 1) * 64 + (((dd >> 3) ^ ((l + 1) & 7)) * 8) + (dd & 7)] = f2bf(v.y);
            sA[(l + 2) * 64 + (((dd >> 3) ^ ((l + 2) & 7)) * 8) + (dd & 7)] = f2bf(v.z);
            sA[(l + 3) * 64 + (((dd >> 3) ^ ((l + 3) & 7)) * 8) + (dd & 7)] = f2bf(v.w);
        }
        // stage B: BC rows 0..127, cols d0..d0+64
#pragma unroll
        for (int p = 0; p < 4; p++) {
            int row = p * 32 + (t >> 3), c8 = t & 7;
            uint4 v = *(const uint4*)(BC + (size_t)row * DM + d0 + c8 * 8);
            *(uint4*)&sB[row * 64 + ((c8 ^ (row & 7)) * 8)] = v;
        }
        __syncthreads();
#pragma unroll
        for (int ks = 0; ks < 2; ks++) {
            bf16x8 af[2], bf[2];
#pragma unroll
            for (int mt = 0; mt < 2; mt++) {
                int r = mt * 16 + m15;
                af[mt] = *(const bf16x8*)&sA[r * 64 + (((ks * 4 + g) ^ (r & 7)) * 8)];
            }
#pragma unroll
            for (int nt = 0; nt < 2; nt++) {
                int r = w * 32 + nt * 16 + m15;
                bf[nt] = *(const bf16x8*)&sB[r * 64 + (((ks * 4 + g) ^ (r & 7)) * 8)];
            }
#pragma unroll
            for (int mt = 0; mt < 2; mt++)
#pragma unroll
                for (int nt = 0; nt < 2; nt++)
                    acc[mt][nt] = __builtin_amdgcn_mfma_f32_16x16x32_bf16(af[mt], bf[nt], acc[mt][nt], 0, 0, 0);
        }
    }
    // epilogue: C[m=l][n=wn]
#pragma unroll
    for (int mt = 0; mt < 2; mt++)
#pragma unroll
        for (int nt = 0; nt < 2; nt++) {
            int wn = w * 32 + nt * 16 + m15;
            unsigned short* dst = (wn < 64) ? BuT : CuT;
            int n = wn & 63;
#pragma unroll
            for (int r = 0; r < 4; r++) {
                int l = l0 + mt * 16 + g * 4 + r;
                dst[((size_t)b * SL + l) * NS + n] = f2bf(acc[mt][nt][r]);
            }
        }
}

// ---------- kernel 2 (v2): per-chunk G / Bv / Wc via power table ----------
// grid (B*NC) blocks of 256 threads.
// G[l][lp] = sum_n Cu[l,n]*Bu[lp,n]*a_n^(l-lp)  (lp<=l, else 0)
// Bv[n][l] = Bu[l,n]*a_n^(63-l) ; Wc[l][n] = Cu[l,n]*a_n^(l+1)
__global__ __launch_bounds__(256) void k_g(const float* __restrict__ A,
                                           const unsigned short* __restrict__ BuT,
                                           const unsigned short* __restrict__ CuT,
                                           unsigned short* __restrict__ Gw,
                                           unsigned short* __restrict__ Bvw,
                                           unsigned short* __restrict__ Wcw)
{
    __shared__ unsigned short sCu[64 * 64];    // [l][n] linear (uniform-row reads)
    __shared__ unsigned short sBu[8 * 64 * 8]; // [q][l][8] subtiled
    __shared__ unsigned short sP[8 * 66 * 8];  // [q][dl 0..64][8] subtiled
    __shared__ unsigned short sTb[64 * 66];    // [n][l] transpose buffer (pad 66)
    const int cc = blockIdx.x, b = cc >> 5, c = cc & 31;
    const int t = threadIdx.x, lane = t & 63;
    const int l0 = c * TC;
    const size_t gbase = (size_t)cc * 4096;

    // stage Cu/Bu chunk: 512 uint4 each, 2/thread
    {
        const unsigned short* srcC = CuT + ((size_t)b * SL + l0) * NS;
        const unsigned short* srcB = BuT + ((size_t)b * SL + l0) * NS;
#pragma unroll
        for (int p = 0; p < 2; p++) {
            int idx = p * 256 + t;
            int r = idx >> 3, q8 = idx & 7;
            uint4 vc = *(const uint4*)(srcC + (size_t)r * NS + q8 * 8);
            *(uint4*)&sCu[r * 64 + q8 * 8] = vc;
            uint4 vb = *(const uint4*)(srcB + (size_t)r * NS + q8 * 8);
            *(uint4*)&sBu[(q8 * 64 + r) * 8] = vb;
        }
    }
    // build P table: P[dl][n] = a_n^dl, dl = 0..64
    {
        int n = t & 63;
        float an = A[n * NS + n];
        int q = n >> 3, n7 = n & 7;
#pragma unroll 1
        for (int dl = (t >> 6) * 17; dl < (t >> 6) * 17 + 17 && dl <= 64; dl++)
            sP[(q * 66 + dl) * 8 + n7] = f2bf(__powf(an, (float)dl));
    }
    __syncthreads();

    // ---- G: 16 rounds, wave-uniform l, lane = lp ----
#pragma unroll 1
    for (int r = 0; r < 16; r++) {
        int idx = r * 256 + t;
        int l = idx >> 6;             // wave-uniform
        int lp = lane;
        int dl = l - lp;
        float acc = 0.f;
        if (dl >= 0) {
#pragma unroll
            for (int q = 0; q < 8; q++) {
                bf16x8 cu = *(const bf16x8*)&sCu[l * 64 + q * 8];          // uniform bcast
                bf16x8 bu = *(const bf16x8*)&sBu[(q * 64 + lp) * 8];       // lanes consecutive
                bf16x8 pp = *(const bf16x8*)&sP[(q * 66 + dl) * 8];        // lanes consecutive
#pragma unroll
                for (int j = 0; j < 8; j++)
                    acc = fmaf(bf2f((unsigned short)cu[j]) * bf2f((unsigned short)bu[j]),
                               bf2f((unsigned short)pp[j]), acc);
            }
        }
        Gw[gbase + l * 64 + lp] = (dl >= 0) ? f2bf(acc) : (unsigned short)0;
    }

    // ---- Wc[l][n] = Cu[l][n] * P[l+1][n] ----
#pragma unroll 1
    for (int r = 0; r < 16; r++) {
        int idx = r * 256 + t;
        int l = idx >> 6;             // wave-uniform
        int n = lane, q = n >> 3, n7 = n & 7;
        float cu = bf2f(sCu[l * 64 + n]);
        float pv = bf2f(sP[(q * 66 + (l + 1)) * 8 + n7]);
        Wcw[gbase + l * 64 + n] = f2bf(cu * pv);
    }

    // ---- Bv: elementwise into transpose buffer, then coalesced out ----
#pragma unroll 1
    for (int r = 0; r < 16; r++) {
        int idx = r * 256 + t;
        int l = idx >> 6;             // wave-uniform
        int n = lane, q = n >> 3, n7 = n & 7;
        float bu = bf2f(sBu[(q * 64 + l) * 8 + n7]);
        float pv = bf2f(sP[(q * 66 + (63 - l)) * 8 + n7]);
        sTb[n * 66 + l] = f2bf(bu * pv);   // column write, pad-66 -> conflict-free
    }
    __syncthreads();
#pragma unroll 1
    for (int r = 0; r < 16; r++) {
        int idx = r * 256 + t;
        int n = idx >> 6;             // wave-uniform
        int l = lane;
        Bvw[gbase + n * 64 + l] = sTb[n * 66 + l];
    }
}

// ---------- kernel 3: Y_intra + E via MFMA ----------
// grid (4 dslab, NC, B), 256 thr. Y[d][l] = sum_l' u[d][l']G[l][l']; E[d][n] = sum_l' u[d][l']Bv[n][l']
__global__ __launch_bounds__(256) void k_chunk(const float* __restrict__ u,
                                               const unsigned short* __restrict__ Gw,
                                               const unsigned short* __restrict__ Bvw,
                                               unsigned short* __restrict__ Ew,
                                               float* __restrict__ y)
{
    __shared__ unsigned short sU[256 * 64];
    __shared__ unsigned short sG[64 * 64];
    __shared__ unsigned short sV[64 * 64];
    const int slab = blockIdx.x, c = blockIdx.y, b = blockIdx.z;
    const int d0 = slab * 256, l0 = c * TC;
    const int t = threadIdx.x, lane = t & 63, w = t >> 6, g = lane >> 4, m15 = lane & 15;

    {
        size_t gbase = ((size_t)(b * NC + c)) * 4096;
        int rr = t >> 3, c8 = t & 7;
#pragma unroll
        for (int p = 0; p < 2; p++) {
            int r = p * 32 + rr;
            uint4 gv = *(const uint4*)(Gw + gbase + r * 64 + c8 * 8);
            *(uint4*)&sG[r * 64 + ((c8 ^ (r & 7)) * 8)] = gv;
            uint4 vv = *(const uint4*)(Bvw + gbase + r * 64 + c8 * 8);
            *(uint4*)&sV[r * 64 + ((c8 ^ (r & 7)) * 8)] = vv;
        }
    }
#pragma unroll
    for (int p = 0; p < 16; p++) {
        int dd = p * 16 + (t >> 4), f = t & 15;
        float4 v = *(const float4*)&u[((size_t)b * DM + d0 + dd) * SL + l0 + f * 4];
        unsigned lo = (unsigned)f2bf(v.x) | ((unsigned)f2bf(v.y) << 16);
        unsigned hi = (unsigned)f2bf(v.z) | ((unsigned)f2bf(v.w) << 16);
        uint2 pk = { lo, hi };
        *(uint2*)&sU[dd * 64 + (((f >> 1) ^ (dd & 7)) * 8) + (f & 1) * 4] = pk;
    }
    __syncthreads();

    f32x4 accY[4][4], accE[4][4];
#pragma unroll
    for (int i = 0; i < 4; i++)
#pragma unroll
        for (int j = 0; j < 4; j++) {
            accY[i][j] = (f32x4){0.f, 0.f, 0.f, 0.f};
            accE[i][j] = (f32x4){0.f, 0.f, 0.f, 0.f};
        }

#pragma unroll
    for (int ks = 0; ks < 2; ks++) {
        bf16x8 af[4];
#pragma unroll
        for (int mt = 0; mt < 4; mt++) {
            int r = w * 64 + mt * 16 + m15;
            af[mt] = *(const bf16x8*)&sU[r * 64 + (((ks * 4 + g) ^ (r & 7)) * 8)];
        }
#pragma unroll
        for (int nt = 0; nt < 4; nt++) {
            int rg = nt * 16 + m15;
            bf16x8 bg = *(const bf16x8*)&sG[rg * 64 + (((ks * 4 + g) ^ (rg & 7)) * 8)];
            bf16x8 bv = *(const bf16x8*)&sV[rg * 64 + (((ks * 4 + g) ^ (rg & 7)) * 8)];
#pragma unroll
            for (int mt = 0; mt < 4; mt++) {
                accY[mt][nt] = __builtin_amdgcn_mfma_f32_16x16x32_bf16(af[mt], bg, accY[mt][nt], 0, 0, 0);
                accE[mt][nt] = __builtin_amdgcn_mfma_f32_16x16x32_bf16(af[mt], bv, accE[mt][nt], 0, 0, 0);
            }
        }
    }
#pragma unroll
    for (int mt = 0; mt < 4; mt++)
#pragma unroll
        for (int nt = 0; nt < 4; nt++)
#pragma unroll
            for (int r = 0; r < 4; r++) {
                int d = d0 + w * 64 + mt * 16 + g * 4 + r;
                int l = l0 + nt * 16 + m15;
                y[((size_t)b * DM + d) * SL + l] = accY[mt][nt][r];
                Ew[(((size_t)b * NC + c) * DM + d) * NS + nt * 16 + m15] = f2bf(accE[mt][nt][r]);
            }
}

// ---------- kernel 4: prefix over chunks (E -> HS in place) ----------
__global__ __launch_bounds__(256) void k_prefix(const float* __restrict__ A,
                                                __hip_bfloat16* __restrict__ E)
{
    int gg = blockIdx.x * 256 + threadIdx.x;
    int ng = gg & 3;
    int d = (gg >> 2) & (DM - 1);
    int b = gg >> 12;
    int n0 = ng * 16;

    v2f aT[8];
#pragma unroll
    for (int j = 0; j < 8; j++) {
        float a0 = A[(n0 + 2 * j) * NS + (n0 + 2 * j)];
        float a1 = A[(n0 + 2 * j + 1) * NS + (n0 + 2 * j + 1)];
        aT[j].x = __powf(a0, (float)TC);
        aT[j].y = __powf(a1, (float)TC);
    }
    v2f hs[8];
#pragma unroll
    for (int j = 0; j < 8; j++) hs[j] = (v2f){0.f, 0.f};

#pragma unroll 1
    for (int c = 0; c < NC; c++) {
        unsigned int* p = (unsigned int*)(E + (((size_t)b * NC + c) * DM + d) * NS + n0);
        uint4 e0 = *(uint4*)p;
        uint4 e1 = *(uint4*)(p + 4);
        unsigned int ew[8] = { e0.x, e0.y, e0.z, e0.w, e1.x, e1.y, e1.z, e1.w };
        unsigned int sw[8];
#pragma unroll
        for (int j = 0; j < 8; j++) {
            __hip_bfloat162 tp;
            tp.x = __float2bfloat16(hs[j].x);
            tp.y = __float2bfloat16(hs[j].y);
            unsigned int wv; memcpy(&wv, &tp, 4);
            sw[j] = wv;
        }
        uint4 s0 = { sw[0], sw[1], sw[2], sw[3] };
        uint4 s1 = { sw[4], sw[5], sw[6], sw[7] };
        *(uint4*)p = s0;
        *(uint4*)(p + 4) = s1;
#pragma unroll
        for (int j = 0; j < 8; j++)
            hs[j] = __builtin_elementwise_fma(aT[j], hs[j], bfpair_to_v2f(ew[j]));
    }
}

// ---------- kernel 5: cross-chunk correction via MFMA ----------
// grid (4 dslab, NC-1, B). y[d][l] += sum_n HS[d][n] * Wc[l][n]
__global__ __launch_bounds__(256) void k_corr(const unsigned short* __restrict__ Ew,
                                              const unsigned short* __restrict__ Wcw,
                                              float* __restrict__ y)
{
    __shared__ unsigned short sH[256 * 64];
    __shared__ unsigned short sW[64 * 64];
    const int slab = blockIdx.x, c = blockIdx.y + 1, b = blockIdx.z;
    const int d0 = slab * 256, l0 = c * TC;
    const int t = threadIdx.x, lane = t & 63, w = t >> 6, g = lane >> 4, m15 = lane & 15;

    {
        int rr = t >> 3, c8 = t & 7;
#pragma unroll
        for (int p = 0; p < 8; p++) {
            int r = p * 32 + rr;
            uint4 v = *(const uint4*)(Ew + (((size_t)b * NC + c) * DM + d0 + r) * NS + c8 * 8);
            *(uint4*)&sH[r * 64 + ((c8 ^ (r & 7)) * 8)] = v;
        }
        size_t wbase = ((size_t)(b * NC + c)) * 4096;
#pragma unroll
        for (int p = 0; p < 2; p++) {
            int r = p * 32 + rr;
            uint4 v = *(const uint4*)(Wcw + wbase + r * 64 + c8 * 8);
            *(uint4*)&sW[r * 64 + ((c8 ^ (r & 7)) * 8)] = v;
        }
    }
    __syncthreads();

    f32x4 acc[4][4];
#pragma unroll
    for (int i = 0; i < 4; i++)
#pragma unroll
        for (int j = 0; j < 4; j++) acc[i][j] = (f32x4){0.f, 0.f, 0.f, 0.f};

#pragma unroll
    for (int ks = 0; ks < 2; ks++) {
        bf16x8 af[4];
#pragma unroll
        for (int mt = 0; mt < 4; mt++) {
            int r = w * 64 + mt * 16 + m15;
            af[mt] = *(const bf16x8*)&sH[r * 64 + (((ks * 4 + g) ^ (r & 7)) * 8)];
        }
#pragma unroll
        for (int nt = 0; nt < 4; nt++) {
            int rg = nt * 16 + m15;
            bf16x8 bw = *(const bf16x8*)&sW[rg * 64 + (((ks * 4 + g) ^ (rg & 7)) * 8)];
#pragma unroll
            for (int mt = 0; mt < 4; mt++)
                acc[mt][nt] = __builtin_amdgcn_mfma_f32_16x16x32_bf16(af[mt], bw, acc[mt][nt], 0, 0, 0);
        }
    }
#pragma unroll
    for (int mt = 0; mt < 4; mt++)
#pragma unroll
        for (int nt = 0; nt < 4; nt++)
#pragma unroll
            for (int r = 0; r < 4; r++) {
                int d = d0 + w * 64 + mt * 16 + g * 4 + r;
                int l = l0 + nt * 16 + m15;
                float* p = &y[((size_t)b * DM + d) * SL + l];
                *p = *p + acc[mt][nt][r];
            }
}

extern "C" void kernel_launch(void* const* d_in, const int* in_sizes, int n_in,
                              void* d_out, int out_size, void* d_ws, size_t ws_size,
                              hipStream_t stream) {
    const float* u = (const float*)d_in[1];
    const float* A = (const float*)d_in[2];
    const float* B = (const float*)d_in[3];
    const float* C = (const float*)d_in[4];
    float* y = (float*)d_out;

    char* base = (char*)d_ws;
    unsigned short* BuT = (unsigned short*)(base);
    unsigned short* CuT = (unsigned short*)(base + (2u << 20));
    unsigned short* BT  = (unsigned short*)(base + (4u << 20));            // [128][DM] with CT
    unsigned short* Gw  = (unsigned short*)(base + (5u << 20));
    unsigned short* Bvw = (unsigned short*)(base + (7u << 20));
    unsigned short* Wcw = (unsigned short*)(base + (9u << 20));
    unsigned short* Ew  = (unsigned short*)(base + (11u << 20));
    unsigned short* CT  = BT + (size_t)NS * DM;

    k_prep<<<dim3(DM / 64, 2), 256, 0, stream>>>(B, C, BT, CT);
    k_proj<<<dim3(SL / 32, BATCH), 256, 0, stream>>>(u, BT, BuT, CuT);
    k_g<<<dim3(BATCH * NC), 256, 0, stream>>>(A, BuT, CuT, Gw, Bvw, Wcw);
    k_chunk<<<dim3(4, NC, BATCH), 256, 0, stream>>>(u, Gw, Bvw, Ew, y);
    k_prefix<<<dim3(BATCH * DM * 4 / 256), 256, 0, stream>>>(A, (__hip_bfloat16*)Ew);
    k_corr<<<dim3(4, NC - 1, BATCH), 256, 0, stream>>>(Ew, Wcw, y);
}

// Round 9
// 121.729 us; speedup vs baseline: 3.9100x; 1.0752x over previous
//
#include <hip/hip_runtime.h>
#include <hip/hip_bf16.h>
#include <string.h>

#define BATCH 8
#define DM 1024
#define NS 64
#define SL 2048
#define NC 32
#define TC 64

typedef __attribute__((ext_vector_type(8))) short bf16x8;
typedef __attribute__((ext_vector_type(4))) float f32x4;
typedef float v2f __attribute__((ext_vector_type(2)));

__device__ inline unsigned short f2bf(float f) {
    union { float f; unsigned u; } v; v.f = f;
    return (unsigned short)((v.u + 0x7fffu + ((v.u >> 16) & 1u)) >> 16);
}
__device__ inline float bf2f(unsigned short h) {
    return __uint_as_float(((unsigned)h) << 16);
}
static __device__ inline v2f bfpair_to_v2f(unsigned int p) {
    unsigned int lo = p << 16, hi = p & 0xffff0000u;
    v2f r; r.x = __uint_as_float(lo); r.y = __uint_as_float(hi); return r;
}

// ws layout (bytes):
//  BuT bf16 [B][SL][NS]      off  0MB  (2MB)
//  CuT bf16 [B][SL][NS]      off  2MB  (2MB)
//  BT  bf16 [NS][DM]         off  4MB  (128KB)
//  CT  bf16 [NS][DM]         off  4MB+128KB
//  G   bf16 [B][NC][64][64]  off  5MB  (2MB)
//  Bv  bf16 [B][NC][64][64]  off  7MB  (2MB)
//  Wc  bf16 [B][NC][64][64]  off  9MB  (2MB)
//  E   bf16 [B][NC][DM][NS]  off 11MB  (32MB)   -> total 43MB

// ---------- kernel 0: transpose B,C -> BT,CT bf16 [n][d] ----------
__global__ __launch_bounds__(256) void k_prep(const float* __restrict__ Bm,
                                              const float* __restrict__ Cm,
                                              unsigned short* __restrict__ BT,
                                              unsigned short* __restrict__ CT)
{
    __shared__ float sT[64][65];
    const float* src = blockIdx.y ? Cm : Bm;
    unsigned short* dst = blockIdx.y ? CT : BT;
    const int d0 = blockIdx.x * 64, t = threadIdx.x;
    {
        int r = t >> 2, f = (t & 3) * 16;
#pragma unroll
        for (int i = 0; i < 4; i++) {
            float4 v = *(const float4*)&src[(size_t)(d0 + r) * NS + f + i * 4];
            sT[r][f + i * 4 + 0] = v.x; sT[r][f + i * 4 + 1] = v.y;
            sT[r][f + i * 4 + 2] = v.z; sT[r][f + i * 4 + 3] = v.w;
        }
    }
    __syncthreads();
    {
        int n = t >> 2, dq = (t & 3) * 16;
        unsigned pk[8];
#pragma unroll
        for (int k = 0; k < 8; k++) {
            unsigned short a = f2bf(sT[dq + 2 * k][n]);
            unsigned short bb = f2bf(sT[dq + 2 * k + 1][n]);
            pk[k] = (unsigned)a | ((unsigned)bb << 16);
        }
        uint4 v0 = { pk[0], pk[1], pk[2], pk[3] };
        uint4 v1 = { pk[4], pk[5], pk[6], pk[7] };
        *(uint4*)&dst[(size_t)n * DM + d0 + dq] = v0;
        *(uint4*)&dst[(size_t)n * DM + d0 + dq + 8] = v1;
    }
}

// ---------- kernel 1: Bu/Cu projections via MFMA ----------
// grid (SL/32, B), 256 thr. out[l][n] = sum_d u[d][l] * BC[n][d]
__global__ __launch_bounds__(256) void k_proj(const float* __restrict__ u,
                                              const unsigned short* __restrict__ BC, // [128][DM]
                                              unsigned short* __restrict__ BuT,
                                              unsigned short* __restrict__ CuT)
{
    __shared__ unsigned short sA[32 * 64];   // [l][d] swz
    __shared__ unsigned short sB[128 * 64];  // [n][d] swz
    const int b = blockIdx.y, l0 = blockIdx.x * 32, t = threadIdx.x;
    const int lane = t & 63, w = t >> 6, g = lane >> 4, m15 = lane & 15;

    f32x4 acc[2][2];
#pragma unroll
    for (int i = 0; i < 2; i++)
#pragma unroll
        for (int j = 0; j < 2; j++) acc[i][j] = (f32x4){0.f, 0.f, 0.f, 0.f};

#pragma unroll 1
    for (int d0 = 0; d0 < DM; d0 += 64) {
        __syncthreads();
        // stage A: u[d0..d0+64][l0..l0+32] -> sA[l][d] bf16 swizzled
#pragma unroll
        for (int p = 0; p < 2; p++) {
            int dd = p * 32 + (t >> 3), f = t & 7;
            float4 v = *(const float4*)&u[((size_t)b * DM + d0 + dd) * SL + l0 + f * 4];
            int l = f * 4;
            sA[(l + 0) * 64 + (((dd >> 3) ^ ((l + 0) & 7)) * 8) + (dd & 7)] = f2bf(v.x);
            sA[(l + 1) * 64 + (((dd >> 3) ^ ((l + 1) & 7)) * 8) + (dd & 7)] = f2bf(v.y);
            sA[(l + 2) * 64 + (((dd >> 3) ^ ((l + 2) & 7)) * 8) + (dd & 7)] = f2bf(v.z);
            sA[(l + 3) * 64 + (((dd >> 3) ^ ((l + 3) & 7)) * 8) + (dd & 7)] = f2bf(v.w);
        }
        // stage B: BC rows 0..127, cols d0..d0+64
#pragma unroll
        for (int p = 0; p < 4; p++) {
            int row = p * 32 + (t >> 3), c8 = t & 7;
            uint4 v = *(const uint4*)(BC + (size_t)row * DM + d0 + c8 * 8);
            *(uint4*)&sB[row * 64 + ((c8 ^ (row & 7)) * 8)] = v;
        }
        __syncthreads();
#pragma unroll
        for (int ks = 0; ks < 2; ks++) {
            bf16x8 af[2], bf[2];
#pragma unroll
            for (int mt = 0; mt < 2; mt++) {
                int r = mt * 16 + m15;
                af[mt] = *(const bf16x8*)&sA[r * 64 + (((ks * 4 + g) ^ (r & 7)) * 8)];
            }
#pragma unroll
            for (int nt = 0; nt < 2; nt++) {
                int r = w * 32 + nt * 16 + m15;
                bf[nt] = *(const bf16x8*)&sB[r * 64 + (((ks * 4 + g) ^ (r & 7)) * 8)];
            }
#pragma unroll
            for (int mt = 0; mt < 2; mt++)
#pragma unroll
                for (int nt = 0; nt < 2; nt++)
                    acc[mt][nt] = __builtin_amdgcn_mfma_f32_16x16x32_bf16(af[mt], bf[nt], acc[mt][nt], 0, 0, 0);
        }
    }
    // epilogue: C[m=l][n=wn]
#pragma unroll
    for (int mt = 0; mt < 2; mt++)
#pragma unroll
        for (int nt = 0; nt < 2; nt++) {
            int wn = w * 32 + nt * 16 + m15;
            unsigned short* dst = (wn < 64) ? BuT : CuT;
            int n = wn & 63;
#pragma unroll
            for (int r = 0; r < 4; r++) {
                int l = l0 + mt * 16 + g * 4 + r;
                dst[((size_t)b * SL + l) * NS + n] = f2bf(acc[mt][nt][r]);
            }
        }
}

// ---------- kernel 2: per-chunk G / Bv / Wc via power table ----------
// grid (B*NC) blocks of 256 threads.
// G[l][lp] = sum_n Cu[l,n]*Bu[lp,n]*a_n^(l-lp)  (lp<=l, else 0)
// Bv[n][l] = Bu[l,n]*a_n^(63-l) ; Wc[l][n] = Cu[l,n]*a_n^(l+1)
__global__ __launch_bounds__(256) void k_g(const float* __restrict__ A,
                                           const unsigned short* __restrict__ BuT,
                                           const unsigned short* __restrict__ CuT,
                                           unsigned short* __restrict__ Gw,
                                           unsigned short* __restrict__ Bvw,
                                           unsigned short* __restrict__ Wcw)
{
    __shared__ unsigned short sCu[64 * 64];    // [l][n] linear (uniform-row reads)
    __shared__ unsigned short sBu[8 * 64 * 8]; // [q][l][8] subtiled
    __shared__ unsigned short sP[8 * 66 * 8];  // [q][dl 0..64][8] subtiled
    __shared__ unsigned short sTb[64 * 66];    // [n][l] transpose buffer (pad 66)
    const int cc = blockIdx.x, b = cc >> 5, c = cc & 31;
    const int t = threadIdx.x, lane = t & 63;
    const int l0 = c * TC;
    const size_t gbase = (size_t)cc * 4096;

    // stage Cu/Bu chunk: 512 uint4 each, 2/thread
    {
        const unsigned short* srcC = CuT + ((size_t)b * SL + l0) * NS;
        const unsigned short* srcB = BuT + ((size_t)b * SL + l0) * NS;
#pragma unroll
        for (int p = 0; p < 2; p++) {
            int idx = p * 256 + t;
            int r = idx >> 3, q8 = idx & 7;
            uint4 vc = *(const uint4*)(srcC + (size_t)r * NS + q8 * 8);
            *(uint4*)&sCu[r * 64 + q8 * 8] = vc;
            uint4 vb = *(const uint4*)(srcB + (size_t)r * NS + q8 * 8);
            *(uint4*)&sBu[(q8 * 64 + r) * 8] = vb;
        }
    }
    // build P table: P[dl][n] = a_n^dl, dl = 0..64
    {
        int n = t & 63;
        float an = A[n * NS + n];
        int q = n >> 3, n7 = n & 7;
#pragma unroll 1
        for (int dl = (t >> 6) * 17; dl < (t >> 6) * 17 + 17 && dl <= 64; dl++)
            sP[(q * 66 + dl) * 8 + n7] = f2bf(__powf(an, (float)dl));
    }
    __syncthreads();

    // ---- G: 16 rounds, wave-uniform l, lane = lp ----
#pragma unroll 1
    for (int r = 0; r < 16; r++) {
        int idx = r * 256 + t;
        int l = idx >> 6;             // wave-uniform
        int lp = lane;
        int dl = l - lp;
        float acc = 0.f;
        if (dl >= 0) {
#pragma unroll
            for (int q = 0; q < 8; q++) {
                bf16x8 cu = *(const bf16x8*)&sCu[l * 64 + q * 8];          // uniform bcast
                bf16x8 bu = *(const bf16x8*)&sBu[(q * 64 + lp) * 8];       // lanes consecutive
                bf16x8 pp = *(const bf16x8*)&sP[(q * 66 + dl) * 8];        // lanes consecutive
#pragma unroll
                for (int j = 0; j < 8; j++)
                    acc = fmaf(bf2f((unsigned short)cu[j]) * bf2f((unsigned short)bu[j]),
                               bf2f((unsigned short)pp[j]), acc);
            }
        }
        Gw[gbase + l * 64 + lp] = (dl >= 0) ? f2bf(acc) : (unsigned short)0;
    }

    // ---- Wc[l][n] = Cu[l][n] * P[l+1][n] ----
#pragma unroll 1
    for (int r = 0; r < 16; r++) {
        int idx = r * 256 + t;
        int l = idx >> 6;             // wave-uniform
        int n = lane, q = n >> 3, n7 = n & 7;
        float cu = bf2f(sCu[l * 64 + n]);
        float pv = bf2f(sP[(q * 66 + (l + 1)) * 8 + n7]);
        Wcw[gbase + l * 64 + n] = f2bf(cu * pv);
    }

    // ---- Bv: elementwise into transpose buffer, then coalesced out ----
#pragma unroll 1
    for (int r = 0; r < 16; r++) {
        int idx = r * 256 + t;
        int l = idx >> 6;             // wave-uniform
        int n = lane, q = n >> 3, n7 = n & 7;
        float bu = bf2f(sBu[(q * 64 + l) * 8 + n7]);
        float pv = bf2f(sP[(q * 66 + (63 - l)) * 8 + n7]);
        sTb[n * 66 + l] = f2bf(bu * pv);   // column write, pad-66 -> conflict-free
    }
    __syncthreads();
#pragma unroll 1
    for (int r = 0; r < 16; r++) {
        int idx = r * 256 + t;
        int n = idx >> 6;             // wave-uniform
        int l = lane;
        Bvw[gbase + n * 64 + l] = sTb[n * 66 + l];
    }
}

// ---------- kernel 3: Y_intra + E via MFMA ----------
// grid (4 dslab, NC, B), 256 thr. Y[d][l] = sum_l' u[d][l']G[l][l']; E[d][n] = sum_l' u[d][l']Bv[n][l']
__global__ __launch_bounds__(256) void k_chunk(const float* __restrict__ u,
                                               const unsigned short* __restrict__ Gw,
                                               const unsigned short* __restrict__ Bvw,
                                               unsigned short* __restrict__ Ew,
                                               float* __restrict__ y)
{
    __shared__ unsigned short sU[256 * 64];
    __shared__ unsigned short sG[64 * 64];
    __shared__ unsigned short sV[64 * 64];
    const int slab = blockIdx.x, c = blockIdx.y, b = blockIdx.z;
    const int d0 = slab * 256, l0 = c * TC;
    const int t = threadIdx.x, lane = t & 63, w = t >> 6, g = lane >> 4, m15 = lane & 15;

    {
        size_t gbase = ((size_t)(b * NC + c)) * 4096;
        int rr = t >> 3, c8 = t & 7;
#pragma unroll
        for (int p = 0; p < 2; p++) {
            int r = p * 32 + rr;
            uint4 gv = *(const uint4*)(Gw + gbase + r * 64 + c8 * 8);
            *(uint4*)&sG[r * 64 + ((c8 ^ (r & 7)) * 8)] = gv;
            uint4 vv = *(const uint4*)(Bvw + gbase + r * 64 + c8 * 8);
            *(uint4*)&sV[r * 64 + ((c8 ^ (r & 7)) * 8)] = vv;
        }
    }
#pragma unroll
    for (int p = 0; p < 16; p++) {
        int dd = p * 16 + (t >> 4), f = t & 15;
        float4 v = *(const float4*)&u[((size_t)b * DM + d0 + dd) * SL + l0 + f * 4];
        unsigned lo = (unsigned)f2bf(v.x) | ((unsigned)f2bf(v.y) << 16);
        unsigned hi = (unsigned)f2bf(v.z) | ((unsigned)f2bf(v.w) << 16);
        uint2 pk = { lo, hi };
        *(uint2*)&sU[dd * 64 + (((f >> 1) ^ (dd & 7)) * 8) + (f & 1) * 4] = pk;
    }
    __syncthreads();

    f32x4 accY[4][4], accE[4][4];
#pragma unroll
    for (int i = 0; i < 4; i++)
#pragma unroll
        for (int j = 0; j < 4; j++) {
            accY[i][j] = (f32x4){0.f, 0.f, 0.f, 0.f};
            accE[i][j] = (f32x4){0.f, 0.f, 0.f, 0.f};
        }

#pragma unroll
    for (int ks = 0; ks < 2; ks++) {
        bf16x8 af[4];
#pragma unroll
        for (int mt = 0; mt < 4; mt++) {
            int r = w * 64 + mt * 16 + m15;
            af[mt] = *(const bf16x8*)&sU[r * 64 + (((ks * 4 + g) ^ (r & 7)) * 8)];
        }
#pragma unroll
        for (int nt = 0; nt < 4; nt++) {
            int rg = nt * 16 + m15;
            bf16x8 bg = *(const bf16x8*)&sG[rg * 64 + (((ks * 4 + g) ^ (rg & 7)) * 8)];
            bf16x8 bv = *(const bf16x8*)&sV[rg * 64 + (((ks * 4 + g) ^ (rg & 7)) * 8)];
#pragma unroll
            for (int mt = 0; mt < 4; mt++) {
                accY[mt][nt] = __builtin_amdgcn_mfma_f32_16x16x32_bf16(af[mt], bg, accY[mt][nt], 0, 0, 0);
                accE[mt][nt] = __builtin_amdgcn_mfma_f32_16x16x32_bf16(af[mt], bv, accE[mt][nt], 0, 0, 0);
            }
        }
    }
#pragma unroll
    for (int mt = 0; mt < 4; mt++)
#pragma unroll
        for (int nt = 0; nt < 4; nt++)
#pragma unroll
            for (int r = 0; r < 4; r++) {
                int d = d0 + w * 64 + mt * 16 + g * 4 + r;
                int l = l0 + nt * 16 + m15;
                y[((size_t)b * DM + d) * SL + l] = accY[mt][nt][r];
                Ew[(((size_t)b * NC + c) * DM + d) * NS + nt * 16 + m15] = f2bf(accE[mt][nt][r]);
            }
}

// ---------- kernel 4 (v2): prefix over chunks (E -> HS in place), 8x parallel ----------
// one thread per (b, d, n-pair): 262144 threads, coalesced 4B accesses.
__global__ __launch_bounds__(256) void k_prefix(const float* __restrict__ A,
                                                unsigned short* __restrict__ E)
{
    int gg = blockIdx.x * 256 + threadIdx.x;     // 0 .. B*DM*32-1
    int p  = gg & 31;                            // n-pair
    int d  = (gg >> 5) & (DM - 1);
    int b  = gg >> 15;
    int n0 = p * 2;

    float a0 = A[n0 * NS + n0];
    float a1 = A[(n0 + 1) * NS + (n0 + 1)];
    v2f aT = { __powf(a0, (float)TC), __powf(a1, (float)TC) };
    v2f hs = { 0.f, 0.f };

    unsigned int* base = (unsigned int*)E + ((((size_t)b * NC) * DM + d) * NS >> 1) + p;
    const size_t cstride = ((size_t)DM * NS) >> 1;

#pragma unroll 4
    for (int c = 0; c < NC; c++) {
        unsigned int* ptr = base + (size_t)c * cstride;
        unsigned int e = *ptr;
        unsigned int sw = (unsigned)f2bf(hs.x) | ((unsigned)f2bf(hs.y) << 16);
        *ptr = sw;                                // state at START of chunk c
        hs = __builtin_elementwise_fma(aT, hs, bfpair_to_v2f(e));
    }
}

// ---------- kernel 5: cross-chunk correction via MFMA ----------
// grid (4 dslab, NC-1, B). y[d][l] += sum_n HS[d][n] * Wc[l][n]
__global__ __launch_bounds__(256) void k_corr(const unsigned short* __restrict__ Ew,
                                              const unsigned short* __restrict__ Wcw,
                                              float* __restrict__ y)
{
    __shared__ unsigned short sH[256 * 64];
    __shared__ unsigned short sW[64 * 64];
    const int slab = blockIdx.x, c = blockIdx.y + 1, b = blockIdx.z;
    const int d0 = slab * 256, l0 = c * TC;
    const int t = threadIdx.x, lane = t & 63, w = t >> 6, g = lane >> 4, m15 = lane & 15;

    {
        int rr = t >> 3, c8 = t & 7;
#pragma unroll
        for (int p = 0; p < 8; p++) {
            int r = p * 32 + rr;
            uint4 v = *(const uint4*)(Ew + (((size_t)b * NC + c) * DM + d0 + r) * NS + c8 * 8);
            *(uint4*)&sH[r * 64 + ((c8 ^ (r & 7)) * 8)] = v;
        }
        size_t wbase = ((size_t)(b * NC + c)) * 4096;
#pragma unroll
        for (int p = 0; p < 2; p++) {
            int r = p * 32 + rr;
            uint4 v = *(const uint4*)(Wcw + wbase + r * 64 + c8 * 8);
            *(uint4*)&sW[r * 64 + ((c8 ^ (r & 7)) * 8)] = v;
        }
    }
    __syncthreads();

    f32x4 acc[4][4];
#pragma unroll
    for (int i = 0; i < 4; i++)
#pragma unroll
        for (int j = 0; j < 4; j++) acc[i][j] = (f32x4){0.f, 0.f, 0.f, 0.f};

#pragma unroll
    for (int ks = 0; ks < 2; ks++) {
        bf16x8 af[4];
#pragma unroll
        for (int mt = 0; mt < 4; mt++) {
            int r = w * 64 + mt * 16 + m15;
            af[mt] = *(const bf16x8*)&sH[r * 64 + (((ks * 4 + g) ^ (r & 7)) * 8)];
        }
#pragma unroll
        for (int nt = 0; nt < 4; nt++) {
            int rg = nt * 16 + m15;
            bf16x8 bw = *(const bf16x8*)&sW[rg * 64 + (((ks * 4 + g) ^ (rg & 7)) * 8)];
#pragma unroll
            for (int mt = 0; mt < 4; mt++)
                acc[mt][nt] = __builtin_amdgcn_mfma_f32_16x16x32_bf16(af[mt], bw, acc[mt][nt], 0, 0, 0);
        }
    }
#pragma unroll
    for (int mt = 0; mt < 4; mt++)
#pragma unroll
        for (int nt = 0; nt < 4; nt++)
#pragma unroll
            for (int r = 0; r < 4; r++) {
                int d = d0 + w * 64 + mt * 16 + g * 4 + r;
                int l = l0 + nt * 16 + m15;
                float* p = &y[((size_t)b * DM + d) * SL + l];
                *p = *p + acc[mt][nt][r];
            }
}

extern "C" void kernel_launch(void* const* d_in, const int* in_sizes, int n_in,
                              void* d_out, int out_size, void* d_ws, size_t ws_size,
                              hipStream_t stream) {
    const float* u = (const float*)d_in[1];
    const float* A = (const float*)d_in[2];
    const float* B = (const float*)d_in[3];
    const float* C = (const float*)d_in[4];
    float* y = (float*)d_out;

    char* base = (char*)d_ws;
    unsigned short* BuT = (unsigned short*)(base);
    unsigned short* CuT = (unsigned short*)(base + (2u << 20));
    unsigned short* BT  = (unsigned short*)(base + (4u << 20));            // [128][DM] with CT
    unsigned short* Gw  = (unsigned short*)(base + (5u << 20));
    unsigned short* Bvw = (unsigned short*)(base + (7u << 20));
    unsigned short* Wcw = (unsigned short*)(base + (9u << 20));
    unsigned short* Ew  = (unsigned short*)(base + (11u << 20));
    unsigned short* CT  = BT + (size_t)NS * DM;

    k_prep<<<dim3(DM / 64, 2), 256, 0, stream>>>(B, C, BT, CT);
    k_proj<<<dim3(SL / 32, BATCH), 256, 0, stream>>>(u, BT, BuT, CuT);
    k_g<<<dim3(BATCH * NC), 256, 0, stream>>>(A, BuT, CuT, Gw, Bvw, Wcw);
    k_chunk<<<dim3(4, NC, BATCH), 256, 0, stream>>>(u, Gw, Bvw, Ew, y);
    k_prefix<<<dim3(BATCH * DM * 32 / 256), 256, 0, stream>>>(A, Ew);
    k_corr<<<dim3(4, NC - 1, BATCH), 256, 0, stream>>>(Ew, Wcw, y);
}